// Round 2
// baseline (858.712 us; speedup 1.0000x reference)
//
#include <hip/hip_runtime.h>

// ---------------------------------------------------------------------------
// IntraModalityEnhance: windowed attention (W=31 window + pos + fsq keys)
// B=2, S=2048, D=1024, H=16, HD=64, E=1024.  fp32 in / fp32 out (per reference);
// internal compute bf16 MFMA + fp32 accumulate (2% tolerance mode).
//
// Decomposition:
//   Qp[s, h*64+e]            = fsq @ Wq + bq          (2048 x 1024)  bf16
//   Kp[r, h*64+e], r<4096    = x   @ Wk + bk          (rows b*2048+s)
//           r in [4096,6144) = fsq @ Wk + bk
//           r in [6144,8192) = pos @ Wk + bk
//   Vp analogous with Wv/bv.
//   attn: per (b,h,s): 33 keys = {x rows s-15..s+15 (OOB -> bias vec),
//                                 pos row s, fsq row s}
//   out = Att @ Wo + bo      (4096 x 1024)  fp32 -> d_out
// ---------------------------------------------------------------------------

typedef __attribute__((ext_vector_type(8))) short bf16x8;   // 8 bf16 = 4 VGPRs
typedef __attribute__((ext_vector_type(4))) float f32x4;

typedef unsigned short u16;
typedef unsigned int u32;

__device__ __forceinline__ float bf2f(u16 u) {
  union { u32 i; float f; } v; v.i = ((u32)u) << 16; return v.f;
}
__device__ __forceinline__ u16 f2bf(float f) {
  union { float f; u32 i; } v; v.f = f;
  u32 r = v.i + 0x7fffu + ((v.i >> 16) & 1u);   // round-to-nearest-even
  return (u16)(r >> 16);
}

// ---------------------------------------------------------------------------
// Batched 64x64-tile transpose with fp32->bf16 convert:
//   out[z][c][r] = bf16(in[z][r][c]).  R,C multiples of 64.
// ---------------------------------------------------------------------------
__global__ __launch_bounds__(256) void transpose64_f2b(const float* __restrict__ in,
                                                       u16* __restrict__ out,
                                                       int R, int C) {
  __shared__ u16 tile[64][72];   // +8 pad to spread banks
  const size_t zoff = (size_t)blockIdx.z * R * C;
  const float* src = in + zoff;
  u16* dst = out + zoff;
  int r0 = blockIdx.y * 64, c0 = blockIdx.x * 64;
  int t = threadIdx.x;
#pragma unroll
  for (int i = 0; i < 16; ++i) {
    int idx = i * 256 + t;
    int r = idx >> 6, c = idx & 63;
    tile[r][c] = f2bf(src[(size_t)(r0 + r) * C + (c0 + c)]);
  }
  __syncthreads();
#pragma unroll
  for (int i = 0; i < 16; ++i) {
    int idx = i * 256 + t;
    int c = idx >> 6, r = idx & 63;
    dst[(size_t)(c0 + c) * R + (r0 + r)] = tile[r][c];
  }
}

// ---------------------------------------------------------------------------
// C[M,1024] = A[M,1024] @ BT^T + bias, fp32 accum.
//   A  : M x 1024 row-major; fp32 if A_F32 (converted to bf16 during staging),
//        else bf16 (u16).
//   BT : 1024(n) x 1024(k) row-major bf16 (i.e. B transposed)
//   C  : fp32 if OUT_F32 else bf16.
// Tile: BM=BN=128, BK=32; 4 waves, each 64x64 quadrant = 4x4 MFMA 16x16x32.
// LDS rows padded 32->40 elems (80 B) so ds_read_b128 is 2-way (free).
// Grid: (N/128, M/128). M,N,K multiples of tile sizes -> no bounds checks.
// ---------------------------------------------------------------------------
#define LDP 40

template <bool A_F32, bool OUT_F32>
__global__ __launch_bounds__(256) void gemm_bt(const void* __restrict__ Ap,
                                               const u16* __restrict__ BT,
                                               const float* __restrict__ bias,
                                               void* __restrict__ Cp) {
  __shared__ u16 As[128 * LDP];
  __shared__ u16 Bs[128 * LDP];
  const int K = 1024, N = 1024;

  const int tile_m = blockIdx.y * 128;
  const int tile_n = blockIdx.x * 128;
  const int t = threadIdx.x;
  const int lane = t & 63, wave = t >> 6;
  const int wm = (wave >> 1) * 64, wn = (wave & 1) * 64;
  const int row16 = lane & 15, quad = lane >> 4;

  // staging coords: 512 chunks of 8 elems; 2 per thread
  const int st_r0 = (t + 0) >> 2,   st_c0 = ((t + 0) & 3) * 8;
  const int st_r1 = (t + 256) >> 2, st_c1 = ((t + 256) & 3) * 8;

  f32x4 acc[4][4] = {};

  for (int k0 = 0; k0 < K; k0 += 32) {
    __syncthreads();
    if (A_F32) {
      const float* A = (const float*)Ap;
      union { u16 h[8]; uint4 q; } u0, u1;
      float4 f0 = *(const float4*)(&A[(size_t)(tile_m + st_r0) * K + k0 + st_c0]);
      float4 f1 = *(const float4*)(&A[(size_t)(tile_m + st_r0) * K + k0 + st_c0 + 4]);
      u0.h[0] = f2bf(f0.x); u0.h[1] = f2bf(f0.y); u0.h[2] = f2bf(f0.z); u0.h[3] = f2bf(f0.w);
      u0.h[4] = f2bf(f1.x); u0.h[5] = f2bf(f1.y); u0.h[6] = f2bf(f1.z); u0.h[7] = f2bf(f1.w);
      *(uint4*)(&As[st_r0 * LDP + st_c0]) = u0.q;
      float4 f2 = *(const float4*)(&A[(size_t)(tile_m + st_r1) * K + k0 + st_c1]);
      float4 f3 = *(const float4*)(&A[(size_t)(tile_m + st_r1) * K + k0 + st_c1 + 4]);
      u1.h[0] = f2bf(f2.x); u1.h[1] = f2bf(f2.y); u1.h[2] = f2bf(f2.z); u1.h[3] = f2bf(f2.w);
      u1.h[4] = f2bf(f3.x); u1.h[5] = f2bf(f3.y); u1.h[6] = f2bf(f3.z); u1.h[7] = f2bf(f3.w);
      *(uint4*)(&As[st_r1 * LDP + st_c1]) = u1.q;
    } else {
      const u16* A = (const u16*)Ap;
      *(uint4*)(&As[st_r0 * LDP + st_c0]) =
          *(const uint4*)(&A[(size_t)(tile_m + st_r0) * K + k0 + st_c0]);
      *(uint4*)(&As[st_r1 * LDP + st_c1]) =
          *(const uint4*)(&A[(size_t)(tile_m + st_r1) * K + k0 + st_c1]);
    }
    *(uint4*)(&Bs[st_r0 * LDP + st_c0]) =
        *(const uint4*)(&BT[(size_t)(tile_n + st_r0) * K + k0 + st_c0]);
    *(uint4*)(&Bs[st_r1 * LDP + st_c1]) =
        *(const uint4*)(&BT[(size_t)(tile_n + st_r1) * K + k0 + st_c1]);
    __syncthreads();

    bf16x8 a_frag[4], b_frag[4];
#pragma unroll
    for (int i = 0; i < 4; ++i)
      a_frag[i] = *(const bf16x8*)(&As[(wm + i * 16 + row16) * LDP + quad * 8]);
#pragma unroll
    for (int j = 0; j < 4; ++j)
      b_frag[j] = *(const bf16x8*)(&Bs[(wn + j * 16 + row16) * LDP + quad * 8]);
#pragma unroll
    for (int i = 0; i < 4; ++i)
#pragma unroll
      for (int j = 0; j < 4; ++j)
        acc[i][j] = __builtin_amdgcn_mfma_f32_16x16x32_bf16(
            a_frag[i], b_frag[j], acc[i][j], 0, 0, 0);
  }

  // Epilogue. C/D layout: col = lane&15, row = quad*4 + reg.
#pragma unroll
  for (int j = 0; j < 4; ++j) {
    int n = tile_n + wn + j * 16 + row16;
    float bv = bias[n];
#pragma unroll
    for (int i = 0; i < 4; ++i) {
      int m0 = tile_m + wm + i * 16 + quad * 4;
#pragma unroll
      for (int r = 0; r < 4; ++r) {
        float val = acc[i][j][r] + bv;
        if (OUT_F32)
          ((float*)Cp)[(size_t)(m0 + r) * N + n] = val;
        else
          ((u16*)Cp)[(size_t)(m0 + r) * N + n] = f2bf(val);
      }
    }
  }
}

// ---------------------------------------------------------------------------
// Windowed attention. One wave per (b,h,s); lane = head-dim element e.
// 33 keys: k<31 -> x-row s+k-15 (OOB -> bias vector), k=31 -> pos, k=32 -> fsq.
// Qp/Kp/Vp bf16; bk/bv fp32; Out bf16.
// ---------------------------------------------------------------------------
__global__ __launch_bounds__(256) void attn_win(const u16* __restrict__ Qp,
                                                const u16* __restrict__ Kp,
                                                const u16* __restrict__ Vp,
                                                const float* __restrict__ bk,
                                                const float* __restrict__ bv,
                                                u16* __restrict__ Out) {
  const int t = threadIdx.x;
  const int lane = t & 63, wv = t >> 6;
  const int gw = blockIdx.x * 4 + wv;   // 0 .. 65535
  const int s = gw & 2047;
  const int h = (gw >> 11) & 15;
  const int b = gw >> 15;
  const int col = h * 64 + lane;

  const float q = bf2f(Qp[(size_t)s * 1024 + col]) * 0.125f;  // 1/sqrt(64)
  const float bkc = bk[col], bvc = bv[col];

  float scores[33];
#pragma unroll
  for (int k = 0; k < 33; ++k) {
    float kv;
    if (k < 31) {
      int ts = s + k - 15;
      kv = (ts >= 0 && ts < 2048)
               ? bf2f(Kp[(size_t)(b * 2048 + ts) * 1024 + col])
               : bkc;
    } else if (k == 31) {
      kv = bf2f(Kp[(size_t)(6144 + s) * 1024 + col]);   // pos row
    } else {
      kv = bf2f(Kp[(size_t)(4096 + s) * 1024 + col]);   // fsq row
    }
    float p = q * kv;
#pragma unroll
    for (int m = 32; m >= 1; m >>= 1) p += __shfl_xor(p, m, 64);
    scores[k] = p;
  }

  float mx = -1e30f;
#pragma unroll
  for (int k = 0; k < 33; ++k) mx = fmaxf(mx, scores[k]);
  float l = 0.f;
#pragma unroll
  for (int k = 0; k < 33; ++k) { scores[k] = __expf(scores[k] - mx); l += scores[k]; }
  const float inv = 1.0f / l;

  float acc = 0.f;
#pragma unroll
  for (int k = 0; k < 33; ++k) {
    float vv;
    if (k < 31) {
      int ts = s + k - 15;
      vv = (ts >= 0 && ts < 2048)
               ? bf2f(Vp[(size_t)(b * 2048 + ts) * 1024 + col])
               : bvc;
    } else if (k == 31) {
      vv = bf2f(Vp[(size_t)(6144 + s) * 1024 + col]);
    } else {
      vv = bf2f(Vp[(size_t)(4096 + s) * 1024 + col]);
    }
    acc += scores[k] * vv;
  }

  Out[(size_t)(b * 2048 + s) * 1024 + col] = f2bf(acc * inv);
}

// ---------------------------------------------------------------------------
extern "C" void kernel_launch(void* const* d_in, const int* in_sizes, int n_in,
                              void* d_out, int out_size, void* d_ws, size_t ws_size,
                              hipStream_t stream) {
  (void)in_sizes; (void)n_in; (void)out_size; (void)ws_size;

  const float* x   = (const float*)d_in[0];
  const float* fsq = (const float*)d_in[1];
  const float* pos = (const float*)d_in[2];
  const float* Wq  = (const float*)d_in[3];
  const float* bq  = (const float*)d_in[4];
  const float* Wk  = (const float*)d_in[5];
  const float* bk  = (const float*)d_in[6];
  const float* Wv  = (const float*)d_in[7];
  const float* bv  = (const float*)d_in[8];
  const float* Wo  = (const float*)d_in[9];
  const float* bo  = (const float*)d_in[10];

  u16* ws = (u16*)d_ws;
  const size_t M1 = 1024 * 1024;           // 1M elems
  u16* WqT = ws + 0 * M1;                  // 1M : (H*HD) x D  bf16
  u16* WkT = ws + 1 * M1;                  // 1M
  u16* WvT = ws + 2 * M1;                  // 1M
  u16* WoT = ws + 3 * M1;                  // 1M : E x (H*HD)
  u16* Qp  = ws + 4 * M1;                  // 2M : 2048 x 1024 bf16
  u16* Kp  = ws + 6 * M1;                  // 8M : 8192 x 1024 bf16
  u16* Vp  = ws + 14 * M1;                 // 8M
  u16* Att = ws + 22 * M1;                 // 4M : 4096 x 1024 bf16
  // total 26M u16 = 52 MB of ws

  // Weight transposes (+convert to bf16): Wq/Wk/Wv are (H=16, D=1024, HD=64)
  // -> per-head 64x1024, landing at flat [(h*64+e), d].  Wo: plain 1024x1024.
  transpose64_f2b<<<dim3(1, 16, 16), 256, 0, stream>>>(Wq, WqT, 1024, 64);
  transpose64_f2b<<<dim3(1, 16, 16), 256, 0, stream>>>(Wk, WkT, 1024, 64);
  transpose64_f2b<<<dim3(1, 16, 16), 256, 0, stream>>>(Wv, WvT, 1024, 64);
  transpose64_f2b<<<dim3(16, 16, 1), 256, 0, stream>>>(Wo, WoT, 1024, 1024);

  // Projections (fp32 A, bf16 out; all K=N=1024; grid = (N/128, M/128))
  gemm_bt<true, false><<<dim3(8, 16), 256, 0, stream>>>(fsq, WqT, bq, Qp);                // Q
  gemm_bt<true, false><<<dim3(8, 32), 256, 0, stream>>>(x,   WkT, bk, Kp);                // K: x
  gemm_bt<true, false><<<dim3(8, 16), 256, 0, stream>>>(fsq, WkT, bk, Kp + 4096 * 1024);  // K: fsq
  gemm_bt<true, false><<<dim3(8, 16), 256, 0, stream>>>(pos, WkT, bk, Kp + 6144 * 1024);  // K: pos
  gemm_bt<true, false><<<dim3(8, 32), 256, 0, stream>>>(x,   WvT, bv, Vp);                // V: x
  gemm_bt<true, false><<<dim3(8, 16), 256, 0, stream>>>(fsq, WvT, bv, Vp + 4096 * 1024);  // V: fsq
  gemm_bt<true, false><<<dim3(8, 16), 256, 0, stream>>>(pos, WvT, bv, Vp + 6144 * 1024);  // V: pos

  // Attention: 65536 waves (one per b,h,s), 4 waves per block
  attn_win<<<16384, 256, 0, stream>>>(Qp, Kp, Vp, bk, bv, Att);

  // Output projection: bf16 A, fp32 out straight into d_out
  gemm_bt<false, true><<<dim3(8, 32), 256, 0, stream>>>(Att, WoT, bo, (float*)d_out);
}

// Round 3
// 318.010 us; speedup vs baseline: 2.7003x; 2.7003x over previous
//
#include <hip/hip_runtime.h>

// ---------------------------------------------------------------------------
// IntraModalityEnhance — fp32 in/out, bf16 MFMA internals.
// B=2, S=2048, D=1024, H=16, HD=64, E=1024, W=31 (+pos,+fsq keys = 33).
//
//  f2b8        : fsq,pos -> bf16
//  transpose64 : Wq/Wk/Wv (H,D,HD)->(H*HD,D) bf16 ; Wo -> Wo^T bf16
//  proj_gemm   : ONE launch, 1152 blocks:
//                  Kp[8192,1024], Vp[8192,1024] from A=[x(4096,fp32);fsqb;posb]
//                  Qp[2048,1024] from fsqb         (m97-style global_load_lds)
//  attn_tile   : block=(b,h,32 s-positions), LDS-staged, no cross-lane ops
//  out_gemm    : Att[4096,1024] @ WoT + bo -> d_out fp32
// ---------------------------------------------------------------------------

typedef __attribute__((ext_vector_type(8))) short bf16x8;
typedef __attribute__((ext_vector_type(4))) float f32x4;
typedef unsigned short u16;
typedef unsigned int u32;

__device__ __forceinline__ float bf2f(u16 u) {
  union { u32 i; float f; } v; v.i = ((u32)u) << 16; return v.f;
}
__device__ __forceinline__ u16 f2bf(float f) {
  union { float f; u32 i; } v; v.f = f;
  u32 r = v.i + 0x7fffu + ((v.i >> 16) & 1u);
  return (u16)(r >> 16);
}
__device__ __forceinline__ float2 unpk(u32 u) {
  union { u32 i; float f; } lo, hi;
  lo.i = u << 16; hi.i = u & 0xffff0000u;
  return make_float2(lo.f, hi.f);
}
__device__ __forceinline__ float dot8(uint4 a, uint4 b) {
  float s = 0.f;
  { float2 x = unpk(a.x), y = unpk(b.x); s += x.x*y.x + x.y*y.y; }
  { float2 x = unpk(a.y), y = unpk(b.y); s += x.x*y.x + x.y*y.y; }
  { float2 x = unpk(a.z), y = unpk(b.z); s += x.x*y.x + x.y*y.y; }
  { float2 x = unpk(a.w), y = unpk(b.w); s += x.x*y.x + x.y*y.y; }
  return s;
}
__device__ __forceinline__ void gload_lds16(const u16* g, u16* l) {
  __builtin_amdgcn_global_load_lds((const __attribute__((address_space(1))) void*)(g),
                                   (__attribute__((address_space(3))) void*)(l),
                                   16, 0, 0);
}

// ---------------------------------------------------------------------------
__global__ __launch_bounds__(256) void f2b8(const float* __restrict__ in,
                                            u16* __restrict__ out, int n8) {
  int i = blockIdx.x * 256 + threadIdx.x;
  if (i >= n8) return;
  float4 a = ((const float4*)in)[2 * i];
  float4 b = ((const float4*)in)[2 * i + 1];
  union { u16 h[8]; uint4 q; } u;
  u.h[0] = f2bf(a.x); u.h[1] = f2bf(a.y); u.h[2] = f2bf(a.z); u.h[3] = f2bf(a.w);
  u.h[4] = f2bf(b.x); u.h[5] = f2bf(b.y); u.h[6] = f2bf(b.z); u.h[7] = f2bf(b.w);
  ((uint4*)out)[i] = u.q;
}

// ---------------------------------------------------------------------------
__global__ __launch_bounds__(256) void transpose64_f2b(const float* __restrict__ in,
                                                       u16* __restrict__ out,
                                                       int R, int C) {
  __shared__ u16 tile[64][72];
  const size_t zoff = (size_t)blockIdx.z * R * C;
  const float* src = in + zoff;
  u16* dst = out + zoff;
  int r0 = blockIdx.y * 64, c0 = blockIdx.x * 64;
  int t = threadIdx.x;
#pragma unroll
  for (int i = 0; i < 16; ++i) {
    int idx = i * 256 + t;
    int r = idx >> 6, c = idx & 63;
    tile[r][c] = f2bf(src[(size_t)(r0 + r) * C + (c0 + c)]);
  }
  __syncthreads();
#pragma unroll
  for (int i = 0; i < 16; ++i) {
    int idx = i * 256 + t;
    int c = idx >> 6, r = idx & 63;
    dst[(size_t)(c0 + c) * R + (r0 + r)] = tile[r][c];
  }
}

// ---------------------------------------------------------------------------
// m97-style GEMM body: 128x128 tile, BK=32, unpadded LDS, global_load_lds x16
// for bf16 A/B; fp32 A staged manually with convert.  K=N=1024 fixed.
// Ap/Cp are pre-offset to the tile's first row; tile_n offsets BT rows / C cols.
// ---------------------------------------------------------------------------
template <bool OUTF32>
__device__ __forceinline__ void gemm_body(const void* Ap, bool af32,
                                          const u16* __restrict__ BT,
                                          const float* __restrict__ bias,
                                          void* Cp, int tile_n) {
  __shared__ u16 As[128 * 32];
  __shared__ u16 Bs[128 * 32];
  const int t = threadIdx.x, lane = t & 63, wave = t >> 6;
  const int wm = (wave >> 1) * 64, wn = (wave & 1) * 64;
  const int row16 = lane & 15, quad = lane >> 4;
  const int srow = wave * 32 + (lane >> 2);   // staging row (call 0)
  const int scol = (lane & 3) * 8;            // staging col (8 bf16 = 16 B)
  // manual fp32 path coords
  const int mr0 = t >> 2, mc = (t & 3) * 8;   // rows 0..63 ; +64 for chunk 1

  f32x4 acc[4][4] = {};

  for (int k0 = 0; k0 < 1024; k0 += 32) {
    __syncthreads();
    if (af32) {
      const float* A = (const float*)Ap;
      union { u16 h[8]; uint4 q; } u0, u1;
      float4 f0 = *(const float4*)(&A[(size_t)mr0 * 1024 + k0 + mc]);
      float4 f1 = *(const float4*)(&A[(size_t)mr0 * 1024 + k0 + mc + 4]);
      u0.h[0]=f2bf(f0.x); u0.h[1]=f2bf(f0.y); u0.h[2]=f2bf(f0.z); u0.h[3]=f2bf(f0.w);
      u0.h[4]=f2bf(f1.x); u0.h[5]=f2bf(f1.y); u0.h[6]=f2bf(f1.z); u0.h[7]=f2bf(f1.w);
      *(uint4*)(&As[mr0 * 32 + mc]) = u0.q;
      float4 f2 = *(const float4*)(&A[(size_t)(mr0 + 64) * 1024 + k0 + mc]);
      float4 f3 = *(const float4*)(&A[(size_t)(mr0 + 64) * 1024 + k0 + mc + 4]);
      u1.h[0]=f2bf(f2.x); u1.h[1]=f2bf(f2.y); u1.h[2]=f2bf(f2.z); u1.h[3]=f2bf(f2.w);
      u1.h[4]=f2bf(f3.x); u1.h[5]=f2bf(f3.y); u1.h[6]=f2bf(f3.z); u1.h[7]=f2bf(f3.w);
      *(uint4*)(&As[(mr0 + 64) * 32 + mc]) = u1.q;
    } else {
      const u16* A = (const u16*)Ap;
      gload_lds16(A + (size_t)srow * 1024 + k0 + scol, &As[wave * 1024]);
      gload_lds16(A + (size_t)(srow + 16) * 1024 + k0 + scol, &As[wave * 1024 + 512]);
    }
    gload_lds16(BT + (size_t)(tile_n + srow) * 1024 + k0 + scol, &Bs[wave * 1024]);
    gload_lds16(BT + (size_t)(tile_n + srow + 16) * 1024 + k0 + scol, &Bs[wave * 1024 + 512]);
    __syncthreads();

    bf16x8 a_frag[4], b_frag[4];
#pragma unroll
    for (int i = 0; i < 4; ++i)
      a_frag[i] = *(const bf16x8*)(&As[(wm + i * 16 + row16) * 32 + quad * 8]);
#pragma unroll
    for (int j = 0; j < 4; ++j)
      b_frag[j] = *(const bf16x8*)(&Bs[(wn + j * 16 + row16) * 32 + quad * 8]);
#pragma unroll
    for (int i = 0; i < 4; ++i)
#pragma unroll
      for (int j = 0; j < 4; ++j)
        acc[i][j] = __builtin_amdgcn_mfma_f32_16x16x32_bf16(
            a_frag[i], b_frag[j], acc[i][j], 0, 0, 0);
  }

  // C/D layout: col = lane&15, row = quad*4 + reg
#pragma unroll
  for (int j = 0; j < 4; ++j) {
    int n = tile_n + wn + j * 16 + row16;
    float bb = bias[n];
#pragma unroll
    for (int i = 0; i < 4; ++i) {
      int m0 = wm + i * 16 + quad * 4;
#pragma unroll
      for (int r = 0; r < 4; ++r) {
        float val = acc[i][j][r] + bb;
        if (OUTF32) ((float*)Cp)[(size_t)(m0 + r) * 1024 + n] = val;
        else        ((u16*)Cp)[(size_t)(m0 + r) * 1024 + n] = f2bf(val);
      }
    }
  }
}

// One launch for all projections: blocks 0..1023 = K/V, 1024..1151 = Q.
__global__ __launch_bounds__(256) void proj_gemm(const float* __restrict__ x,
                                                 const u16* __restrict__ fsqb,
                                                 const u16* __restrict__ posb,
                                                 const u16* __restrict__ WkT,
                                                 const u16* __restrict__ WvT,
                                                 const u16* __restrict__ WqT,
                                                 const float* __restrict__ bk,
                                                 const float* __restrict__ bv,
                                                 const float* __restrict__ bq,
                                                 u16* __restrict__ Kp,
                                                 u16* __restrict__ Vp,
                                                 u16* __restrict__ Qp) {
  int bid = blockIdx.x;
  const void* Ap; bool af32 = false;
  const u16* BT; const float* bias; u16* C; int tile_n;
  if (bid < 1024) {
    int tm = bid >> 4, tn = bid & 15;
    if (tm < 32)      { Ap = x + (size_t)tm * 128 * 1024; af32 = true; }
    else if (tm < 48) { Ap = fsqb + (size_t)(tm - 32) * 128 * 1024; }
    else              { Ap = posb + (size_t)(tm - 48) * 128 * 1024; }
    if (tn < 8) { BT = WkT; bias = bk; C = Kp + (size_t)tm * 128 * 1024; tile_n = tn * 128; }
    else        { BT = WvT; bias = bv; C = Vp + (size_t)tm * 128 * 1024; tile_n = (tn - 8) * 128; }
  } else {
    int q = bid - 1024; int tm = q >> 3; tile_n = (q & 7) * 128;
    Ap = fsqb + (size_t)tm * 128 * 1024; BT = WqT; bias = bq;
    C = Qp + (size_t)tm * 128 * 1024;
  }
  gemm_body<false>(Ap, af32, BT, bias, C, tile_n);
}

__global__ __launch_bounds__(256) void out_gemm(const u16* __restrict__ Att,
                                                const u16* __restrict__ WoT,
                                                const float* __restrict__ bo,
                                                float* __restrict__ Out) {
  int tile_n = blockIdx.x * 128, tm = blockIdx.y;
  gemm_body<true>(Att + (size_t)tm * 128 * 1024, false, WoT, bo,
                  Out + (size_t)tm * 128 * 1024, tile_n);
}

// ---------------------------------------------------------------------------
// Tiled attention: block = (b, h, s-tile of 32).  LDS tables are u32-packed
// bf16 pairs, row stride 33 u32 (odd -> conflict-free).  No cross-lane ops.
// ---------------------------------------------------------------------------
#define OQ  0        // 32 rows
#define OKW 1056     // 62 rows (x-window K)
#define OVW 3102     // 62 rows
#define OKP 5148     // 32 rows (pos K) ; OKF=+1056 ; OVP=+2112 ; OVF=+3168
#define SM_U32 9372

__global__ __launch_bounds__(256) void attn_tile(const u16* __restrict__ Qp,
                                                 const u16* __restrict__ Kp,
                                                 const u16* __restrict__ Vp,
                                                 const float* __restrict__ bk,
                                                 const float* __restrict__ bv,
                                                 u16* __restrict__ Att) {
  __shared__ u32 sm[SM_U32];
  __shared__ float smP[32 * 35];

  const int t = threadIdx.x;
  const int bid = blockIdx.x;
  const int s0 = (bid & 63) * 32;
  const int h = (bid >> 6) & 15;
  const int b = bid >> 10;
  const int hw = t >> 5, lane32 = t & 31;

  // ---- stage 284 rows (each row: 32 u32 = 64 bf16), half-wave per row ----
  for (int r = hw; r < 284; r += 8) {
    u32 val; u32* dst;
    if (r < 32) {                         // Q rows (batch-independent)
      val = *(const u32*)(Qp + (size_t)(s0 + r) * 1024 + h * 64 + (lane32 << 1));
      dst = sm + OQ + r * 33 + lane32;
    } else if (r < 156) {                 // window K (32..93) / V (94..155)
      int isV = (r >= 94);
      int w = isV ? (r - 94) : (r - 32);
      int g = s0 + w - 15;
      const u16* src = isV ? Vp : Kp;
      const float* bb = isV ? bv : bk;
      if ((unsigned)g < 2048u)
        val = *(const u32*)(src + (size_t)(b * 2048 + g) * 1024 + h * 64 + (lane32 << 1));
      else {
        float2 f = *(const float2*)(bb + h * 64 + (lane32 << 1));
        val = (u32)f2bf(f.x) | ((u32)f2bf(f.y) << 16);
      }
      dst = sm + (isV ? OVW : OKW) + w * 33 + lane32;
    } else {                              // KP / KF / VP / VF
      int q = r - 156;
      int which = q >> 5, i = q & 31;
      size_t grow = (which == 0 || which == 2) ? (size_t)(6144 + s0 + i)
                                               : (size_t)(4096 + s0 + i);
      const u16* src = (which < 2) ? Kp : Vp;
      val = *(const u32*)(src + grow * 1024 + h * 64 + (lane32 << 1));
      dst = sm + OKP + which * 1056 + i * 33 + lane32;
    }
    *dst = val;
  }
  __syncthreads();

  // ---- scores: thread = (s = t&31, k = t>>5 + 8*pass) ----
  {
    const int s = t & 31, kbase = t >> 5;
#pragma unroll
    for (int p = 0; p < 5; ++p) {
      int k = kbase + 8 * p;
      if (k < 33) {
        const u32* qr = sm + OQ + s * 33;
        const u32* kr = (k < 31)  ? sm + OKW + (s + k) * 33
                      : (k == 31) ? sm + OKP + s * 33
                                  : sm + OKP + 1056 + s * 33;   // fsq
        float a = 0.f;
#pragma unroll
        for (int c = 0; c < 32; c += 4)
          a += dot8(*(const uint4*)(qr + c), *(const uint4*)(kr + c));
        smP[s * 35 + k] = a * 0.125f;
      }
    }
  }
  __syncthreads();

  // ---- softmax (lanes 0..31 of wave 0) ----
  if (t < 32) {
    float mx = -1e30f;
#pragma unroll
    for (int k = 0; k < 33; ++k) mx = fmaxf(mx, smP[t * 35 + k]);
    float sum = 0.f;
#pragma unroll
    for (int k = 0; k < 33; ++k) {
      float v = __expf(smP[t * 35 + k] - mx);
      smP[t * 35 + k] = v; sum += v;
    }
    float inv = 1.f / sum;
#pragma unroll
    for (int k = 0; k < 33; ++k) smP[t * 35 + k] *= inv;
  }
  __syncthreads();

  // ---- PV: thread = (s = t>>3, 8-elem octet = t&7) ----
  {
    const int s = t >> 3, oct = t & 7;
    float acc[8] = {0,0,0,0,0,0,0,0};
    for (int k = 0; k < 33; ++k) {
      const u32* vr = (k < 31)  ? sm + OVW + (s + k) * 33
                    : (k == 31) ? sm + OKP + 2112 + s * 33    // VP
                                : sm + OKP + 3168 + s * 33;   // VF
      float pk = smP[s * 35 + k];
      uint4 v4 = *(const uint4*)(vr + oct * 4);
      float2 f0 = unpk(v4.x), f1 = unpk(v4.y), f2 = unpk(v4.z), f3 = unpk(v4.w);
      acc[0] += pk * f0.x; acc[1] += pk * f0.y;
      acc[2] += pk * f1.x; acc[3] += pk * f1.y;
      acc[4] += pk * f2.x; acc[5] += pk * f2.y;
      acc[6] += pk * f3.x; acc[7] += pk * f3.y;
    }
    union { u16 hh[8]; uint4 q; } o;
#pragma unroll
    for (int j = 0; j < 8; ++j) o.hh[j] = f2bf(acc[j]);
    *(uint4*)(Att + (size_t)(b * 2048 + s0 + s) * 1024 + h * 64 + oct * 8) = o.q;
  }
}

// ---------------------------------------------------------------------------
extern "C" void kernel_launch(void* const* d_in, const int* in_sizes, int n_in,
                              void* d_out, int out_size, void* d_ws, size_t ws_size,
                              hipStream_t stream) {
  (void)in_sizes; (void)n_in; (void)out_size; (void)ws_size;

  const float* x   = (const float*)d_in[0];
  const float* fsq = (const float*)d_in[1];
  const float* pos = (const float*)d_in[2];
  const float* Wq  = (const float*)d_in[3];
  const float* bq  = (const float*)d_in[4];
  const float* Wk  = (const float*)d_in[5];
  const float* bk  = (const float*)d_in[6];
  const float* Wv  = (const float*)d_in[7];
  const float* bv  = (const float*)d_in[8];
  const float* Wo  = (const float*)d_in[9];
  const float* bo  = (const float*)d_in[10];

  u16* ws = (u16*)d_ws;
  const size_t M1 = 1024 * 1024;
  u16* WqT  = ws + 0 * M1;   // 1M
  u16* WkT  = ws + 1 * M1;   // 1M
  u16* WvT  = ws + 2 * M1;   // 1M
  u16* WoT  = ws + 3 * M1;   // 1M
  u16* Qp   = ws + 4 * M1;   // 2M : 2048x1024
  u16* Kp   = ws + 6 * M1;   // 8M : 8192x1024
  u16* Vp   = ws + 14 * M1;  // 8M
  u16* fsqb = ws + 22 * M1;  // 2M
  u16* posb = ws + 24 * M1;  // 2M
  u16* Att  = ws + 22 * M1;  // 4M, aliases fsqb+posb (dead after proj_gemm)
  // peak 26M u16 = 52 MB (same footprint as the passing round-1 kernel)

  f2b8<<<1024, 256, 0, stream>>>(fsq, fsqb, 262144);
  f2b8<<<1024, 256, 0, stream>>>(pos, posb, 262144);

  transpose64_f2b<<<dim3(1, 16, 16), 256, 0, stream>>>(Wq, WqT, 1024, 64);
  transpose64_f2b<<<dim3(1, 16, 16), 256, 0, stream>>>(Wk, WkT, 1024, 64);
  transpose64_f2b<<<dim3(1, 16, 16), 256, 0, stream>>>(Wv, WvT, 1024, 64);
  transpose64_f2b<<<dim3(16, 16, 1), 256, 0, stream>>>(Wo, WoT, 1024, 1024);

  proj_gemm<<<1152, 256, 0, stream>>>(x, fsqb, posb, WkT, WvT, WqT,
                                      bk, bv, bq, Kp, Vp, Qp);

  attn_tile<<<2048, 256, 0, stream>>>(Qp, Kp, Vp, bk, bv, Att);

  out_gemm<<<dim3(8, 32), 256, 0, stream>>>(Att, WoT, bo, (float*)d_out);
}

// Round 4
// 230.797 us; speedup vs baseline: 3.7206x; 1.3779x over previous
//
#include <hip/hip_runtime.h>

// ---------------------------------------------------------------------------
// IntraModalityEnhance — fp32 in/out, bf16 MFMA internals.
// B=2, S=2048, D=1024, H=16, HD=64, E=1024, W=31 (+pos,+fsq keys = 33).
//
//  f2b8         : x,fsq,pos -> bf16 (once; kills per-tile reconvert in GEMM)
//  transposeQKV : Wq/Wk/Wv (H,D,HD)->(H*HD,D) bf16  (one launch)
//  transpose64  : Wo -> Wo^T bf16
//  proj_gemm    : ONE launch, 1152 blocks, pure global_load_lds m97 GEMM
//  attn_tile    : block=(b,h,32 s), MFMA for QK^T and PV, diag keys via VALU
//  out_gemm     : Att[4096,1024] @ WoT + bo -> d_out fp32
// ---------------------------------------------------------------------------

typedef __attribute__((ext_vector_type(8))) short bf16x8;
typedef __attribute__((ext_vector_type(4))) float f32x4;
typedef unsigned short u16;
typedef unsigned int u32;

__device__ __forceinline__ float bf2f(u16 u) {
  union { u32 i; float f; } v; v.i = ((u32)u) << 16; return v.f;
}
__device__ __forceinline__ u16 f2bf(float f) {
  union { float f; u32 i; } v; v.f = f;
  u32 r = v.i + 0x7fffu + ((v.i >> 16) & 1u);
  return (u16)(r >> 16);
}
__device__ __forceinline__ float2 unpk(u32 u) {
  union { u32 i; float f; } lo, hi;
  lo.i = u << 16; hi.i = u & 0xffff0000u;
  return make_float2(lo.f, hi.f);
}
__device__ __forceinline__ float dot8(uint4 a, uint4 b) {
  float s = 0.f;
  { float2 x = unpk(a.x), y = unpk(b.x); s += x.x*y.x + x.y*y.y; }
  { float2 x = unpk(a.y), y = unpk(b.y); s += x.x*y.x + x.y*y.y; }
  { float2 x = unpk(a.z), y = unpk(b.z); s += x.x*y.x + x.y*y.y; }
  { float2 x = unpk(a.w), y = unpk(b.w); s += x.x*y.x + x.y*y.y; }
  return s;
}
__device__ __forceinline__ void gload_lds16(const u16* g, u16* l) {
  __builtin_amdgcn_global_load_lds((const __attribute__((address_space(1))) void*)(g),
                                   (__attribute__((address_space(3))) void*)(l),
                                   16, 0, 0);
}
__device__ __forceinline__ uint4 pack8(float4 a, float4 b) {
  union { u16 h[8]; uint4 q; } u;
  u.h[0] = f2bf(a.x); u.h[1] = f2bf(a.y); u.h[2] = f2bf(a.z); u.h[3] = f2bf(a.w);
  u.h[4] = f2bf(b.x); u.h[5] = f2bf(b.y); u.h[6] = f2bf(b.z); u.h[7] = f2bf(b.w);
  return u.q;
}

// ---------------------------------------------------------------------------
__global__ __launch_bounds__(256) void f2b8(const float* __restrict__ in,
                                            u16* __restrict__ out, int n8) {
  int i = blockIdx.x * 256 + threadIdx.x;
  if (i >= n8) return;
  float4 a = ((const float4*)in)[2 * i];
  float4 b = ((const float4*)in)[2 * i + 1];
  ((uint4*)out)[i] = pack8(a, b);
}

// ---------------------------------------------------------------------------
__device__ __forceinline__ void transpose_body(const float* src, u16* dst,
                                               int R, int C) {
  __shared__ u16 tile[64][72];
  int r0 = blockIdx.y * 64, c0 = blockIdx.x * 64;
  int t = threadIdx.x;
#pragma unroll
  for (int i = 0; i < 16; ++i) {
    int idx = i * 256 + t;
    int r = idx >> 6, c = idx & 63;
    tile[r][c] = f2bf(src[(size_t)(r0 + r) * C + (c0 + c)]);
  }
  __syncthreads();
#pragma unroll
  for (int i = 0; i < 16; ++i) {
    int idx = i * 256 + t;
    int c = idx >> 6, r = idx & 63;
    dst[(size_t)(c0 + c) * R + (r0 + r)] = tile[r][c];
  }
}

__global__ __launch_bounds__(256) void transpose64_f2b(const float* __restrict__ in,
                                                       u16* __restrict__ out,
                                                       int R, int C) {
  const size_t zoff = (size_t)blockIdx.z * R * C;
  transpose_body(in + zoff, out + zoff, R, C);
}

// One launch for Wq/Wk/Wv: z in [0,48), head = z & 15.
__global__ __launch_bounds__(256) void transposeQKV(const float* __restrict__ Wq,
                                                    const float* __restrict__ Wk,
                                                    const float* __restrict__ Wv,
                                                    u16* __restrict__ WqT,
                                                    u16* __restrict__ WkT,
                                                    u16* __restrict__ WvT) {
  int z = blockIdx.z;
  const float* src; u16* dst;
  if (z < 16)      { src = Wq; dst = WqT; }
  else if (z < 32) { src = Wk; dst = WkT; }
  else             { src = Wv; dst = WvT; }
  const size_t zoff = (size_t)(z & 15) * 1024 * 64;
  transpose_body(src + zoff, dst + zoff, 1024, 64);
}

// ---------------------------------------------------------------------------
// m97-style GEMM body: 128x128 tile, BK=32, unpadded LDS, global_load_lds x16.
// K=N=1024 fixed.  Ap/Cp pre-offset to tile row 0; tile_n offsets BT rows.
// ---------------------------------------------------------------------------
template <bool OUTF32>
__device__ __forceinline__ void gemm_body(const u16* __restrict__ Ap,
                                          const u16* __restrict__ BT,
                                          const float* __restrict__ bias,
                                          void* Cp, int tile_n) {
  __shared__ u16 As[128 * 32];
  __shared__ u16 Bs[128 * 32];
  const int t = threadIdx.x, lane = t & 63, wave = t >> 6;
  const int wm = (wave >> 1) * 64, wn = (wave & 1) * 64;
  const int row16 = lane & 15, quad = lane >> 4;
  const int srow = wave * 32 + (lane >> 2);
  const int scol = (lane & 3) * 8;

  f32x4 acc[4][4] = {};

  for (int k0 = 0; k0 < 1024; k0 += 32) {
    __syncthreads();
    gload_lds16(Ap + (size_t)srow * 1024 + k0 + scol, &As[wave * 1024]);
    gload_lds16(Ap + (size_t)(srow + 16) * 1024 + k0 + scol, &As[wave * 1024 + 512]);
    gload_lds16(BT + (size_t)(tile_n + srow) * 1024 + k0 + scol, &Bs[wave * 1024]);
    gload_lds16(BT + (size_t)(tile_n + srow + 16) * 1024 + k0 + scol, &Bs[wave * 1024 + 512]);
    __syncthreads();

    bf16x8 a_frag[4], b_frag[4];
#pragma unroll
    for (int i = 0; i < 4; ++i)
      a_frag[i] = *(const bf16x8*)(&As[(wm + i * 16 + row16) * 32 + quad * 8]);
#pragma unroll
    for (int j = 0; j < 4; ++j)
      b_frag[j] = *(const bf16x8*)(&Bs[(wn + j * 16 + row16) * 32 + quad * 8]);
#pragma unroll
    for (int i = 0; i < 4; ++i)
#pragma unroll
      for (int j = 0; j < 4; ++j)
        acc[i][j] = __builtin_amdgcn_mfma_f32_16x16x32_bf16(
            a_frag[i], b_frag[j], acc[i][j], 0, 0, 0);
  }

  // C/D layout: col = lane&15, row = quad*4 + reg
#pragma unroll
  for (int j = 0; j < 4; ++j) {
    int n = tile_n + wn + j * 16 + row16;
    float bb = bias[n];
#pragma unroll
    for (int i = 0; i < 4; ++i) {
      int m0 = wm + i * 16 + quad * 4;
#pragma unroll
      for (int r = 0; r < 4; ++r) {
        float val = acc[i][j][r] + bb;
        if (OUTF32) ((float*)Cp)[(size_t)(m0 + r) * 1024 + n] = val;
        else        ((u16*)Cp)[(size_t)(m0 + r) * 1024 + n] = f2bf(val);
      }
    }
  }
}

// blocks 0..1023 = K/V (A = [xb;fsqb;posb]), 1024..1151 = Q (A = fsqb).
__global__ __launch_bounds__(256) void proj_gemm(const u16* __restrict__ xb,
                                                 const u16* __restrict__ fsqb,
                                                 const u16* __restrict__ posb,
                                                 const u16* __restrict__ WkT,
                                                 const u16* __restrict__ WvT,
                                                 const u16* __restrict__ WqT,
                                                 const float* __restrict__ bk,
                                                 const float* __restrict__ bv,
                                                 const float* __restrict__ bq,
                                                 u16* __restrict__ Kp,
                                                 u16* __restrict__ Vp,
                                                 u16* __restrict__ Qp) {
  int bid = blockIdx.x;
  const u16* Ap; const u16* BT; const float* bias; u16* C; int tile_n;
  if (bid < 1024) {
    int tm = bid >> 4, tn = bid & 15;
    if (tm < 32)      Ap = xb   + (size_t)tm * 128 * 1024;
    else if (tm < 48) Ap = fsqb + (size_t)(tm - 32) * 128 * 1024;
    else              Ap = posb + (size_t)(tm - 48) * 128 * 1024;
    if (tn < 8) { BT = WkT; bias = bk; C = Kp + (size_t)tm * 128 * 1024; tile_n = tn * 128; }
    else        { BT = WvT; bias = bv; C = Vp + (size_t)tm * 128 * 1024; tile_n = (tn - 8) * 128; }
  } else {
    int q = bid - 1024; int tm = q >> 3; tile_n = (q & 7) * 128;
    Ap = fsqb + (size_t)tm * 128 * 1024; BT = WqT; bias = bq;
    C = Qp + (size_t)tm * 128 * 1024;
  }
  gemm_body<false>(Ap, BT, bias, C, tile_n);
}

__global__ __launch_bounds__(256) void out_gemm(const u16* __restrict__ Att,
                                                const u16* __restrict__ WoT,
                                                const float* __restrict__ bo,
                                                float* __restrict__ Out) {
  int tile_n = blockIdx.x * 128, tm = blockIdx.y;
  gemm_body<true>(Att + (size_t)tm * 128 * 1024, WoT, bo,
                  Out + (size_t)tm * 128 * 1024, tile_n);
}

// ---------------------------------------------------------------------------
// MFMA attention tile: block = (b, h, 32 s-positions).
// LDS tables (u16, row stride 72 = 16B-aligned, 4-bank row rotation):
//   Qs[32]  KW[64] (rows s0-15..s0+46; OOB->bk)  VT[64 e][w]  KP/KF/VP/VF[32]
//   Ps[32] (bf16 probs, zero outside band)
// smP[32][68] f32: cols 0..63 scores, 64/65 diag scores, 66/67 diag probs.
// ---------------------------------------------------------------------------
#define AST 72
#define QS  0
#define KWS 2304
#define VTS 6912
#define KPS 11520   // +2304: KF, +4608: VP, +6912: VF
#define PS  20736

__global__ __launch_bounds__(256) void attn_tile(const u16* __restrict__ Qp,
                                                 const u16* __restrict__ Kp,
                                                 const u16* __restrict__ Vp,
                                                 const float* __restrict__ bk,
                                                 const float* __restrict__ bv,
                                                 u16* __restrict__ Att) {
  __shared__ u16 sm[23040];
  __shared__ float smP[32 * 68];

  const int t = threadIdx.x;
  const int bid = blockIdx.x;
  const int s0 = (bid & 63) * 32;
  const int h  = (bid >> 6) & 15;
  const int b  = bid >> 10;
  const int lane = t & 63, wave = t >> 6;
  const int row16 = lane & 15, quad = lane >> 4;
  const int hcol = h * 64;

  // ---- staging (uint4 = 16B/lane everywhere) ----
  { int w = t >> 3, oct = t & 7;                       // Q rows
    *(uint4*)&sm[QS + w * AST + oct * 8] =
        *(const uint4*)(Qp + (size_t)(s0 + w) * 1024 + hcol + oct * 8); }
#pragma unroll
  for (int i = 0; i < 2; ++i) {                        // window K rows
    int task = i * 256 + t; int w = task >> 3, oct = task & 7;
    int g = s0 + w - 15;
    uint4 v;
    if ((unsigned)g < 2048u)
      v = *(const uint4*)(Kp + (size_t)(b * 2048 + g) * 1024 + hcol + oct * 8);
    else
      v = pack8(*(const float4*)(bk + hcol + oct * 8),
                *(const float4*)(bk + hcol + oct * 8 + 4));
    *(uint4*)&sm[KWS + w * AST + oct * 8] = v;
  }
#pragma unroll
  for (int i = 0; i < 4; ++i) {                        // KP/KF/VP/VF rows
    int task = i * 256 + t;
    int which = task >> 8, r = (task >> 3) & 31, oct = task & 7;
    const u16* src = (which < 2) ? Kp : Vp;
    size_t grow = ((which & 1) == 0) ? (size_t)(6144 + s0 + r)
                                     : (size_t)(4096 + s0 + r);
    *(uint4*)&sm[KPS + which * 2304 + r * AST + oct * 8] =
        *(const uint4*)(src + grow * 1024 + hcol + oct * 8);
  }
#pragma unroll
  for (int i = 0; i < 2; ++i) {                        // window V rows -> VT
    int task = i * 256 + t; int w = task >> 3, oct = task & 7;
    int g = s0 + w - 15;
    union { u16 h8[8]; uint4 q; } u;
    if ((unsigned)g < 2048u)
      u.q = *(const uint4*)(Vp + (size_t)(b * 2048 + g) * 1024 + hcol + oct * 8);
    else
      u.q = pack8(*(const float4*)(bv + hcol + oct * 8),
                  *(const float4*)(bv + hcol + oct * 8 + 4));
#pragma unroll
    for (int j = 0; j < 8; ++j)
      sm[VTS + (oct * 8 + j) * AST + w] = u.h8[j];
  }
  __syncthreads();

  // ---- scores: wave handles key block [wave*16, wave*16+16) ----
  {
    f32x4 accS[2] = {};
#pragma unroll
    for (int kc = 0; kc < 2; ++kc) {
      bf16x8 bf_ = *(const bf16x8*)&sm[KWS + (wave * 16 + row16) * AST + kc * 32 + quad * 8];
#pragma unroll
      for (int mi = 0; mi < 2; ++mi) {
        bf16x8 af = *(const bf16x8*)&sm[QS + (mi * 16 + row16) * AST + kc * 32 + quad * 8];
        accS[mi] = __builtin_amdgcn_mfma_f32_16x16x32_bf16(af, bf_, accS[mi], 0, 0, 0);
      }
    }
#pragma unroll
    for (int mi = 0; mi < 2; ++mi)
#pragma unroll
      for (int r = 0; r < 4; ++r) {
        int s = mi * 16 + quad * 4 + r;
        int w = wave * 16 + row16;
        float v = accS[mi][r] * 0.125f;
        smP[s * 68 + w] = (w >= s && w <= s + 30) ? v : -1e30f;
      }
  }
  if (t < 64) {                                        // diag scores (pos,fsq)
    int s = t >> 1, which = t & 1;
    int base = KPS + which * 2304;
    float a = 0.f;
#pragma unroll
    for (int c = 0; c < 8; ++c)
      a += dot8(*(const uint4*)&sm[QS + s * AST + c * 8],
                *(const uint4*)&sm[base + s * AST + c * 8]);
    smP[s * 68 + 64 + which] = a * 0.125f;
  }
  __syncthreads();

  // ---- softmax (t<32), write bf16 P band, diag probs stay fp32 ----
  if (t < 32) {
    int s = t;
    float vals[33];
#pragma unroll
    for (int k = 0; k < 31; ++k) vals[k] = smP[s * 68 + s + k];
    vals[31] = smP[s * 68 + 64];
    vals[32] = smP[s * 68 + 65];
    float mx = -1e30f;
#pragma unroll
    for (int k = 0; k < 33; ++k) mx = fmaxf(mx, vals[k]);
    float sum = 0.f;
#pragma unroll
    for (int k = 0; k < 33; ++k) { vals[k] = __expf(vals[k] - mx); sum += vals[k]; }
    float inv = 1.f / sum;
    u32* prow = (u32*)&sm[PS + s * AST];
#pragma unroll
    for (int j = 0; j < 32; ++j) prow[j] = 0;          // zero cols 0..63
#pragma unroll
    for (int k = 0; k < 31; ++k)
      sm[PS + s * AST + s + k] = f2bf(vals[k] * inv);  // band
    smP[s * 68 + 66] = vals[31] * inv;
    smP[s * 68 + 67] = vals[32] * inv;
  }
  __syncthreads();

  // ---- PV: wave handles e block [wave*16, wave*16+16) ----
  {
    f32x4 accO[2] = {};
#pragma unroll
    for (int kc = 0; kc < 2; ++kc) {
      bf16x8 bf_ = *(const bf16x8*)&sm[VTS + (wave * 16 + row16) * AST + kc * 32 + quad * 8];
#pragma unroll
      for (int mi = 0; mi < 2; ++mi) {
        bf16x8 af = *(const bf16x8*)&sm[PS + (mi * 16 + row16) * AST + kc * 32 + quad * 8];
        accO[mi] = __builtin_amdgcn_mfma_f32_16x16x32_bf16(af, bf_, accO[mi], 0, 0, 0);
      }
    }
#pragma unroll
    for (int mi = 0; mi < 2; ++mi)
#pragma unroll
      for (int r = 0; r < 4; ++r) {
        int s = mi * 16 + quad * 4 + r;
        int e = wave * 16 + row16;
        float o = accO[mi][r]
                + smP[s * 68 + 66] * bf2f(sm[KPS + 2 * 2304 + s * AST + e])   // VP
                + smP[s * 68 + 67] * bf2f(sm[KPS + 3 * 2304 + s * AST + e]);  // VF
        Att[(size_t)(b * 2048 + s0 + s) * 1024 + hcol + e] = f2bf(o);
      }
  }
}

// ---------------------------------------------------------------------------
extern "C" void kernel_launch(void* const* d_in, const int* in_sizes, int n_in,
                              void* d_out, int out_size, void* d_ws, size_t ws_size,
                              hipStream_t stream) {
  (void)in_sizes; (void)n_in; (void)out_size; (void)ws_size;

  const float* x   = (const float*)d_in[0];
  const float* fsq = (const float*)d_in[1];
  const float* pos = (const float*)d_in[2];
  const float* Wq  = (const float*)d_in[3];
  const float* bq  = (const float*)d_in[4];
  const float* Wk  = (const float*)d_in[5];
  const float* bk  = (const float*)d_in[6];
  const float* Wv  = (const float*)d_in[7];
  const float* bv  = (const float*)d_in[8];
  const float* Wo  = (const float*)d_in[9];
  const float* bo  = (const float*)d_in[10];

  u16* ws = (u16*)d_ws;
  const size_t M1 = 1024 * 1024;
  u16* WqT  = ws + 0 * M1;   // 1M
  u16* WkT  = ws + 1 * M1;   // 1M
  u16* WvT  = ws + 2 * M1;   // 1M
  u16* WoT  = ws + 3 * M1;   // 1M
  u16* Qp   = ws + 4 * M1;   // 2M : 2048x1024
  u16* Kp   = ws + 6 * M1;   // 8M : 8192x1024
  u16* Vp   = ws + 14 * M1;  // 8M
  u16* fsqb = ws + 22 * M1;  // 2M
  u16* posb = ws + 24 * M1;  // 2M
  u16* xb   = ws + 26 * M1;  // 4M : 4096x1024
  u16* Att  = ws + 22 * M1;  // 4M, aliases fsqb+posb (dead after proj_gemm)
  // peak 30M u16 = 60 MB

  f2b8<<<2048, 256, 0, stream>>>(x, xb, 524288);
  f2b8<<<1024, 256, 0, stream>>>(fsq, fsqb, 262144);
  f2b8<<<1024, 256, 0, stream>>>(pos, posb, 262144);

  transposeQKV<<<dim3(1, 16, 48), 256, 0, stream>>>(Wq, Wk, Wv, WqT, WkT, WvT);
  transpose64_f2b<<<dim3(16, 16, 1), 256, 0, stream>>>(Wo, WoT, 1024, 1024);

  proj_gemm<<<1152, 256, 0, stream>>>(xb, fsqb, posb, WkT, WvT, WqT,
                                      bk, bv, bq, Kp, Vp, Qp);

  attn_tile<<<2048, 256, 0, stream>>>(Qp, Kp, Vp, bk, bv, Att);

  out_gemm<<<dim3(8, 32), 256, 0, stream>>>(Att, WoT, bo, (float*)d_out);
}

// Round 5
// 213.991 us; speedup vs baseline: 4.0128x; 1.0785x over previous
//
#include <hip/hip_runtime.h>

// ---------------------------------------------------------------------------
// IntraModalityEnhance — fp32 in/out, bf16 MFMA internals.
// B=2, S=2048, D=1024, H=16, HD=64, E=1024, W=31 (+pos,+fsq keys = 33).
//
//  f2b_all      : x,fsq,pos -> bf16 (one launch)
//  transpose_all: Wq/Wk/Wv (H,D,HD)->(H*HD,D) + Wo^T, bf16 (one launch)
//  proj_gemm    : ONE launch, 1152 blocks; BK=64, XOR-swizzled LDS,
//                 global_load_lds x16 (bank-conflict-free frag reads)
//  attn_tile    : block=(b,h,32 s), MFMA QK^T/PV, banded fp32 score scratch
//  out_gemm     : Att[4096,1024] @ WoT + bo -> d_out fp32
// ---------------------------------------------------------------------------

typedef __attribute__((ext_vector_type(8))) short bf16x8;
typedef __attribute__((ext_vector_type(4))) float f32x4;
typedef unsigned short u16;
typedef unsigned int u32;

__device__ __forceinline__ float bf2f(u16 u) {
  union { u32 i; float f; } v; v.i = ((u32)u) << 16; return v.f;
}
__device__ __forceinline__ u16 f2bf(float f) {
  union { float f; u32 i; } v; v.f = f;
  u32 r = v.i + 0x7fffu + ((v.i >> 16) & 1u);
  return (u16)(r >> 16);
}
__device__ __forceinline__ float2 unpk(u32 u) {
  union { u32 i; float f; } lo, hi;
  lo.i = u << 16; hi.i = u & 0xffff0000u;
  return make_float2(lo.f, hi.f);
}
__device__ __forceinline__ float dot8(uint4 a, uint4 b) {
  float s = 0.f;
  { float2 x = unpk(a.x), y = unpk(b.x); s += x.x*y.x + x.y*y.y; }
  { float2 x = unpk(a.y), y = unpk(b.y); s += x.x*y.x + x.y*y.y; }
  { float2 x = unpk(a.z), y = unpk(b.z); s += x.x*y.x + x.y*y.y; }
  { float2 x = unpk(a.w), y = unpk(b.w); s += x.x*y.x + x.y*y.y; }
  return s;
}
__device__ __forceinline__ void gload_lds16(const u16* g, u16* l) {
  __builtin_amdgcn_global_load_lds((const __attribute__((address_space(1))) void*)(g),
                                   (__attribute__((address_space(3))) void*)(l),
                                   16, 0, 0);
}
__device__ __forceinline__ uint4 pack8(float4 a, float4 b) {
  union { u16 h[8]; uint4 q; } u;
  u.h[0] = f2bf(a.x); u.h[1] = f2bf(a.y); u.h[2] = f2bf(a.z); u.h[3] = f2bf(a.w);
  u.h[4] = f2bf(b.x); u.h[5] = f2bf(b.y); u.h[6] = f2bf(b.z); u.h[7] = f2bf(b.w);
  return u.q;
}

// ---------------------------------------------------------------------------
// One launch: convert x (524288 8-chunks), fsq (262144), pos (262144) to bf16.
// Boundaries are block-aligned (2048 / 1024 / 1024 blocks) -> uniform branches.
// ---------------------------------------------------------------------------
__global__ __launch_bounds__(256) void f2b_all(const float* __restrict__ x,
                                               const float* __restrict__ fsq,
                                               const float* __restrict__ pos,
                                               u16* __restrict__ xb,
                                               u16* __restrict__ fsqb,
                                               u16* __restrict__ posb) {
  int i = blockIdx.x * 256 + threadIdx.x;
  const float* src; u16* dst; int off;
  if (i < 524288)      { src = x;   dst = xb;   off = i; }
  else if (i < 786432) { src = fsq; dst = fsqb; off = i - 524288; }
  else                 { src = pos; dst = posb; off = i - 786432; }
  float4 a = ((const float4*)src)[2 * off];
  float4 b = ((const float4*)src)[2 * off + 1];
  ((uint4*)dst)[off] = pack8(a, b);
}

// ---------------------------------------------------------------------------
__device__ __forceinline__ void transpose_body(const float* src, u16* dst,
                                               int R, int C, int r0, int c0) {
  __shared__ u16 tile[64][72];
  int t = threadIdx.x;
#pragma unroll
  for (int i = 0; i < 16; ++i) {
    int idx = i * 256 + t;
    int r = idx >> 6, c = idx & 63;
    tile[r][c] = f2bf(src[(size_t)(r0 + r) * C + (c0 + c)]);
  }
  __syncthreads();
#pragma unroll
  for (int i = 0; i < 16; ++i) {
    int idx = i * 256 + t;
    int c = idx >> 6, r = idx & 63;
    dst[(size_t)(c0 + c) * R + (r0 + r)] = tile[r][c];
  }
}

// z=0/1/2: Wq/Wk/Wv head blockIdx.x, row-block blockIdx.y.  z=3: Wo 64x64 tile.
__global__ __launch_bounds__(256) void transpose_all(const float* __restrict__ Wq,
                                                     const float* __restrict__ Wk,
                                                     const float* __restrict__ Wv,
                                                     const float* __restrict__ Wo,
                                                     u16* __restrict__ WqT,
                                                     u16* __restrict__ WkT,
                                                     u16* __restrict__ WvT,
                                                     u16* __restrict__ WoT) {
  int z = blockIdx.z;
  if (z < 3) {
    const float* s = (z == 0) ? Wq : (z == 1) ? Wk : Wv;
    u16* d = (z == 0) ? WqT : (z == 1) ? WkT : WvT;
    size_t off = (size_t)blockIdx.x * 65536;   // head * 1024 * 64
    transpose_body(s + off, d + off, 1024, 64, blockIdx.y * 64, 0);
  } else {
    transpose_body(Wo, WoT, 1024, 1024, blockIdx.y * 64, blockIdx.x * 64);
  }
}

// ---------------------------------------------------------------------------
// GEMM body: 128x128 tile, BK=64, XOR-swizzled LDS, global_load_lds x16.
// LDS chunk (16 B) layout: phys p = r*8 + (c ^ (r & 7))   (c = k-chunk 0..7).
// Staging: wave w, call j: lane l -> phys chunk w*256 + j*64 + l, i.e.
//   r = w*32 + j*8 + (l>>3), global col chunk c = (l&7) ^ ((l>>3)&7).
// Frag reads cover all 8 bank groups over any 8 rows -> 2-way (free).
// K=N=1024 fixed.  Ap/Cp pre-offset to tile row 0; tile_n offsets BT rows.
// ---------------------------------------------------------------------------
__device__ __forceinline__ int swz(int R, int c) {   // u16 index of chunk
  return (R * 8 + (c ^ (R & 7))) * 8;
}

template <bool OUTF32>
__device__ __forceinline__ void gemm_body(const u16* __restrict__ Ap,
                                          const u16* __restrict__ BT,
                                          const float* __restrict__ bias,
                                          void* Cp, int tile_n) {
  __shared__ u16 As[128 * 64];
  __shared__ u16 Bs[128 * 64];
  const int t = threadIdx.x, lane = t & 63, wave = t >> 6;
  const int wm = (wave >> 1) * 64, wn = (wave & 1) * 64;
  const int row16 = lane & 15, quad = lane >> 4;
  const int l8 = lane >> 3;
  const int cswz = (lane & 7) ^ l8;     // source k-chunk for this lane

  f32x4 acc[4][4] = {};

  for (int k0 = 0; k0 < 1024; k0 += 64) {
    __syncthreads();
#pragma unroll
    for (int j = 0; j < 4; ++j) {
      int r = wave * 32 + j * 8 + l8;
      gload_lds16(Ap + (size_t)r * 1024 + k0 + cswz * 8,
                  &As[wave * 2048 + j * 512]);
      gload_lds16(BT + (size_t)(tile_n + r) * 1024 + k0 + cswz * 8,
                  &Bs[wave * 2048 + j * 512]);
    }
    __syncthreads();

#pragma unroll
    for (int kb = 0; kb < 2; ++kb) {
      bf16x8 a_frag[4], b_frag[4];
#pragma unroll
      for (int i = 0; i < 4; ++i)
        a_frag[i] = *(const bf16x8*)&As[swz(wm + i * 16 + row16, kb * 4 + quad)];
#pragma unroll
      for (int j = 0; j < 4; ++j)
        b_frag[j] = *(const bf16x8*)&Bs[swz(wn + j * 16 + row16, kb * 4 + quad)];
#pragma unroll
      for (int i = 0; i < 4; ++i)
#pragma unroll
        for (int j = 0; j < 4; ++j)
          acc[i][j] = __builtin_amdgcn_mfma_f32_16x16x32_bf16(
              a_frag[i], b_frag[j], acc[i][j], 0, 0, 0);
    }
  }

  // C/D layout: col = lane&15, row = quad*4 + reg
#pragma unroll
  for (int j = 0; j < 4; ++j) {
    int n = tile_n + wn + j * 16 + row16;
    float bb = bias[n];
#pragma unroll
    for (int i = 0; i < 4; ++i) {
      int m0 = wm + i * 16 + quad * 4;
#pragma unroll
      for (int r = 0; r < 4; ++r) {
        float val = acc[i][j][r] + bb;
        if (OUTF32) ((float*)Cp)[(size_t)(m0 + r) * 1024 + n] = val;
        else        ((u16*)Cp)[(size_t)(m0 + r) * 1024 + n] = f2bf(val);
      }
    }
  }
}

// blocks 0..1023 = K/V (A = [xb;fsqb;posb]), 1024..1151 = Q (A = fsqb).
__global__ __launch_bounds__(256) void proj_gemm(const u16* __restrict__ xb,
                                                 const u16* __restrict__ fsqb,
                                                 const u16* __restrict__ posb,
                                                 const u16* __restrict__ WkT,
                                                 const u16* __restrict__ WvT,
                                                 const u16* __restrict__ WqT,
                                                 const float* __restrict__ bk,
                                                 const float* __restrict__ bv,
                                                 const float* __restrict__ bq,
                                                 u16* __restrict__ Kp,
                                                 u16* __restrict__ Vp,
                                                 u16* __restrict__ Qp) {
  int bid = blockIdx.x;
  const u16* Ap; const u16* BT; const float* bias; u16* C; int tile_n;
  if (bid < 1024) {
    int tm = bid >> 4, tn = bid & 15;
    if (tm < 32)      Ap = xb   + (size_t)tm * 128 * 1024;
    else if (tm < 48) Ap = fsqb + (size_t)(tm - 32) * 128 * 1024;
    else              Ap = posb + (size_t)(tm - 48) * 128 * 1024;
    if (tn < 8) { BT = WkT; bias = bk; C = Kp + (size_t)tm * 128 * 1024; tile_n = tn * 128; }
    else        { BT = WvT; bias = bv; C = Vp + (size_t)tm * 128 * 1024; tile_n = (tn - 8) * 128; }
  } else {
    int q = bid - 1024; int tm = q >> 3; tile_n = (q & 7) * 128;
    Ap = fsqb + (size_t)tm * 128 * 1024; BT = WqT; bias = bq;
    C = Qp + (size_t)tm * 128 * 1024;
  }
  gemm_body<false>(Ap, BT, bias, C, tile_n);
}

__global__ __launch_bounds__(256) void out_gemm(const u16* __restrict__ Att,
                                                const u16* __restrict__ WoT,
                                                const float* __restrict__ bo,
                                                float* __restrict__ Out) {
  int tile_n = blockIdx.x * 128, tm = blockIdx.y;
  gemm_body<true>(Att + (size_t)tm * 128 * 1024, WoT, bo,
                  Out + (size_t)tm * 128 * 1024, tile_n);
}

// ---------------------------------------------------------------------------
// MFMA attention tile: block = (b, h, 32 s-positions).
// LDS tables (u16, row stride 72; rows rotate 1 chunk/row -> conflict-free):
//   Qs[32]  KW[64] (rows s0-15..s0+46; OOB->bk)  VT[64 e][w]  KP/KF/VP/VF[32]
//   Ps[32] (bf16 probs, zero outside band)
// smP[32][36] f32 banded: col 0..30 = w-s, 31/32 diag scores, 33/34 diag probs.
// Total 50.7 KB -> 3 blocks/CU.
// ---------------------------------------------------------------------------
#define AST 72
#define QS  0
#define KWS 2304
#define VTS 6912
#define KPS 11520   // +2304: KF, +4608: VP, +6912: VF
#define PS  20736

__global__ __launch_bounds__(256) void attn_tile(const u16* __restrict__ Qp,
                                                 const u16* __restrict__ Kp,
                                                 const u16* __restrict__ Vp,
                                                 const float* __restrict__ bk,
                                                 const float* __restrict__ bv,
                                                 u16* __restrict__ Att) {
  __shared__ u16 sm[23040];
  __shared__ float smP[32 * 36];

  const int t = threadIdx.x;
  const int bid = blockIdx.x;
  const int s0 = (bid & 63) * 32;
  const int h  = (bid >> 6) & 15;
  const int b  = bid >> 10;
  const int lane = t & 63, wave = t >> 6;
  const int row16 = lane & 15, quad = lane >> 4;
  const int hcol = h * 64;

  // ---- staging (uint4 = 16B/lane everywhere) ----
  { int w = t >> 3, oct = t & 7;                       // Q rows
    *(uint4*)&sm[QS + w * AST + oct * 8] =
        *(const uint4*)(Qp + (size_t)(s0 + w) * 1024 + hcol + oct * 8); }
#pragma unroll
  for (int i = 0; i < 2; ++i) {                        // window K rows
    int task = i * 256 + t; int w = task >> 3, oct = task & 7;
    int g = s0 + w - 15;
    uint4 v;
    if ((unsigned)g < 2048u)
      v = *(const uint4*)(Kp + (size_t)(b * 2048 + g) * 1024 + hcol + oct * 8);
    else
      v = pack8(*(const float4*)(bk + hcol + oct * 8),
                *(const float4*)(bk + hcol + oct * 8 + 4));
    *(uint4*)&sm[KWS + w * AST + oct * 8] = v;
  }
#pragma unroll
  for (int i = 0; i < 4; ++i) {                        // KP/KF/VP/VF rows
    int task = i * 256 + t;
    int which = task >> 8, r = (task >> 3) & 31, oct = task & 7;
    const u16* src = (which < 2) ? Kp : Vp;
    size_t grow = ((which & 1) == 0) ? (size_t)(6144 + s0 + r)
                                     : (size_t)(4096 + s0 + r);
    *(uint4*)&sm[KPS + which * 2304 + r * AST + oct * 8] =
        *(const uint4*)(src + grow * 1024 + hcol + oct * 8);
  }
#pragma unroll
  for (int i = 0; i < 2; ++i) {                        // window V rows -> VT
    int task = i * 256 + t; int w = task >> 3, oct = task & 7;
    int g = s0 + w - 15;
    union { u16 h8[8]; uint4 q; } u;
    if ((unsigned)g < 2048u)
      u.q = *(const uint4*)(Vp + (size_t)(b * 2048 + g) * 1024 + hcol + oct * 8);
    else
      u.q = pack8(*(const float4*)(bv + hcol + oct * 8),
                  *(const float4*)(bv + hcol + oct * 8 + 4));
#pragma unroll
    for (int j = 0; j < 8; ++j)
      sm[VTS + (oct * 8 + j) * AST + w] = u.h8[j];
  }
  __syncthreads();

  // ---- scores: wave handles key block [wave*16, wave*16+16) ----
  {
    f32x4 accS[2] = {};
#pragma unroll
    for (int kc = 0; kc < 2; ++kc) {
      bf16x8 bf_ = *(const bf16x8*)&sm[KWS + (wave * 16 + row16) * AST + kc * 32 + quad * 8];
#pragma unroll
      for (int mi = 0; mi < 2; ++mi) {
        bf16x8 af = *(const bf16x8*)&sm[QS + (mi * 16 + row16) * AST + kc * 32 + quad * 8];
        accS[mi] = __builtin_amdgcn_mfma_f32_16x16x32_bf16(af, bf_, accS[mi], 0, 0, 0);
      }
    }
#pragma unroll
    for (int mi = 0; mi < 2; ++mi)
#pragma unroll
      for (int r = 0; r < 4; ++r) {
        int s = mi * 16 + quad * 4 + r;
        int w = wave * 16 + row16;
        int d = w - s;
        if (d >= 0 && d <= 30) smP[s * 36 + d] = accS[mi][r] * 0.125f;
      }
  }
  if (t < 64) {                                        // diag scores (pos,fsq)
    int s = t >> 1, which = t & 1;
    int base = KPS + which * 2304;
    float a = 0.f;
#pragma unroll
    for (int c = 0; c < 8; ++c)
      a += dot8(*(const uint4*)&sm[QS + s * AST + c * 8],
                *(const uint4*)&sm[base + s * AST + c * 8]);
    smP[s * 36 + 31 + which] = a * 0.125f;
  }
  __syncthreads();

  // ---- softmax (t<32), write bf16 P band, diag probs stay fp32 ----
  if (t < 32) {
    int s = t;
    float vals[33];
#pragma unroll
    for (int k = 0; k < 33; ++k) vals[k] = smP[s * 36 + k];
    float mx = -1e30f;
#pragma unroll
    for (int k = 0; k < 33; ++k) mx = fmaxf(mx, vals[k]);
    float sum = 0.f;
#pragma unroll
    for (int k = 0; k < 33; ++k) { vals[k] = __expf(vals[k] - mx); sum += vals[k]; }
    float inv = 1.f / sum;
    u32* prow = (u32*)&sm[PS + s * AST];
#pragma unroll
    for (int j = 0; j < 32; ++j) prow[j] = 0;          // zero cols 0..63
#pragma unroll
    for (int k = 0; k < 31; ++k)
      sm[PS + s * AST + s + k] = f2bf(vals[k] * inv);  // band
    smP[s * 36 + 33] = vals[31] * inv;
    smP[s * 36 + 34] = vals[32] * inv;
  }
  __syncthreads();

  // ---- PV: wave handles e block [wave*16, wave*16+16) ----
  {
    f32x4 accO[2] = {};
#pragma unroll
    for (int kc = 0; kc < 2; ++kc) {
      bf16x8 bf_ = *(const bf16x8*)&sm[VTS + (wave * 16 + row16) * AST + kc * 32 + quad * 8];
#pragma unroll
      for (int mi = 0; mi < 2; ++mi) {
        bf16x8 af = *(const bf16x8*)&sm[PS + (mi * 16 + row16) * AST + kc * 32 + quad * 8];
        accO[mi] = __builtin_amdgcn_mfma_f32_16x16x32_bf16(af, bf_, accO[mi], 0, 0, 0);
      }
    }
#pragma unroll
    for (int mi = 0; mi < 2; ++mi)
#pragma unroll
      for (int r = 0; r < 4; ++r) {
        int s = mi * 16 + quad * 4 + r;
        int e = wave * 16 + row16;
        float o = accO[mi][r]
                + smP[s * 36 + 33] * bf2f(sm[KPS + 2 * 2304 + s * AST + e])   // VP
                + smP[s * 36 + 34] * bf2f(sm[KPS + 3 * 2304 + s * AST + e]);  // VF
        Att[(size_t)(b * 2048 + s0 + s) * 1024 + hcol + e] = f2bf(o);
      }
  }
}

// ---------------------------------------------------------------------------
extern "C" void kernel_launch(void* const* d_in, const int* in_sizes, int n_in,
                              void* d_out, int out_size, void* d_ws, size_t ws_size,
                              hipStream_t stream) {
  (void)in_sizes; (void)n_in; (void)out_size; (void)ws_size;

  const float* x   = (const float*)d_in[0];
  const float* fsq = (const float*)d_in[1];
  const float* pos = (const float*)d_in[2];
  const float* Wq  = (const float*)d_in[3];
  const float* bq  = (const float*)d_in[4];
  const float* Wk  = (const float*)d_in[5];
  const float* bk  = (const float*)d_in[6];
  const float* Wv  = (const float*)d_in[7];
  const float* bv  = (const float*)d_in[8];
  const float* Wo  = (const float*)d_in[9];
  const float* bo  = (const float*)d_in[10];

  u16* ws = (u16*)d_ws;
  const size_t M1 = 1024 * 1024;
  u16* WqT  = ws + 0 * M1;   // 1M
  u16* WkT  = ws + 1 * M1;   // 1M
  u16* WvT  = ws + 2 * M1;   // 1M
  u16* WoT  = ws + 3 * M1;   // 1M
  u16* Qp   = ws + 4 * M1;   // 2M : 2048x1024
  u16* Kp   = ws + 6 * M1;   // 8M : 8192x1024
  u16* Vp   = ws + 14 * M1;  // 8M
  u16* fsqb = ws + 22 * M1;  // 2M
  u16* posb = ws + 24 * M1;  // 2M
  u16* xb   = ws + 26 * M1;  // 4M : 4096x1024
  u16* Att  = ws + 22 * M1;  // 4M, aliases fsqb+posb (dead after proj_gemm)
  // peak 30M u16 = 60 MB

  f2b_all<<<4096, 256, 0, stream>>>(x, fsq, pos, xb, fsqb, posb);
  transpose_all<<<dim3(16, 16, 4), 256, 0, stream>>>(Wq, Wk, Wv, Wo,
                                                     WqT, WkT, WvT, WoT);

  proj_gemm<<<1152, 256, 0, stream>>>(xb, fsqb, posb, WkT, WvT, WqT,
                                      bk, bv, bq, Kp, Vp, Qp);

  attn_tile<<<2048, 256, 0, stream>>>(Qp, Kp, Vp, bk, bv, Att);

  out_gemm<<<dim3(8, 32), 256, 0, stream>>>(Att, WoT, bo, (float*)d_out);
}

// Round 6
// 198.930 us; speedup vs baseline: 4.3166x; 1.0757x over previous
//
#include <hip/hip_runtime.h>

// ---------------------------------------------------------------------------
// IntraModalityEnhance — fp32 in/out, bf16 MFMA internals.
// B=2, S=2048, D=1024, H=16, HD=64, E=1024, W=31 (+pos,+fsq keys = 33).
//
//  prep       : ONE launch — x/fsq/pos -> bf16  +  Wq/Wk/Wv/Wo transposes
//  proj_gemm  : ONE launch, 1152 blocks; BK=64, XOR-swizzled LDS,
//               global_load_lds x16 (conflict-free frag reads)
//  attn_tile  : block=(b,h,32 s), MFMA QK^T/PV; ~37 KB LDS (4 blocks/CU):
//               P-band reuses Q rows, diag-V read from global in epilogue
//  out_gemm   : BM=64 tiles -> 512 blocks, Att @ WoT + bo -> d_out fp32
// ---------------------------------------------------------------------------

typedef __attribute__((ext_vector_type(8))) short bf16x8;
typedef __attribute__((ext_vector_type(4))) float f32x4;
typedef unsigned short u16;
typedef unsigned int u32;

__device__ __forceinline__ float bf2f(u16 u) {
  union { u32 i; float f; } v; v.i = ((u32)u) << 16; return v.f;
}
__device__ __forceinline__ u16 f2bf(float f) {
  union { float f; u32 i; } v; v.f = f;
  u32 r = v.i + 0x7fffu + ((v.i >> 16) & 1u);
  return (u16)(r >> 16);
}
__device__ __forceinline__ float2 unpk(u32 u) {
  union { u32 i; float f; } lo, hi;
  lo.i = u << 16; hi.i = u & 0xffff0000u;
  return make_float2(lo.f, hi.f);
}
__device__ __forceinline__ float dot8(uint4 a, uint4 b) {
  float s = 0.f;
  { float2 x = unpk(a.x), y = unpk(b.x); s += x.x*y.x + x.y*y.y; }
  { float2 x = unpk(a.y), y = unpk(b.y); s += x.x*y.x + x.y*y.y; }
  { float2 x = unpk(a.z), y = unpk(b.z); s += x.x*y.x + x.y*y.y; }
  { float2 x = unpk(a.w), y = unpk(b.w); s += x.x*y.x + x.y*y.y; }
  return s;
}
__device__ __forceinline__ void gload_lds16(const u16* g, u16* l) {
  __builtin_amdgcn_global_load_lds((const __attribute__((address_space(1))) void*)(g),
                                   (__attribute__((address_space(3))) void*)(l),
                                   16, 0, 0);
}
__device__ __forceinline__ uint4 pack8(float4 a, float4 b) {
  union { u16 h[8]; uint4 q; } u;
  u.h[0] = f2bf(a.x); u.h[1] = f2bf(a.y); u.h[2] = f2bf(a.z); u.h[3] = f2bf(a.w);
  u.h[4] = f2bf(b.x); u.h[5] = f2bf(b.y); u.h[6] = f2bf(b.z); u.h[7] = f2bf(b.w);
  return u.q;
}

// ---------------------------------------------------------------------------
__device__ __forceinline__ void transpose_body(const float* src, u16* dst,
                                               int R, int C, int r0, int c0) {
  __shared__ u16 tile[64][72];
  int t = threadIdx.x;
#pragma unroll
  for (int i = 0; i < 16; ++i) {
    int idx = i * 256 + t;
    int r = idx >> 6, c = idx & 63;
    tile[r][c] = f2bf(src[(size_t)(r0 + r) * C + (c0 + c)]);
  }
  __syncthreads();
#pragma unroll
  for (int i = 0; i < 16; ++i) {
    int idx = i * 256 + t;
    int c = idx >> 6, r = idx & 63;
    dst[(size_t)(c0 + c) * R + (r0 + r)] = tile[r][c];
  }
}

// ONE launch: blocks 0..4095 convert x/fsq/pos; 4096..5119 transpose weights.
__global__ __launch_bounds__(256) void prep(const float* __restrict__ x,
                                            const float* __restrict__ fsq,
                                            const float* __restrict__ pos,
                                            const float* __restrict__ Wq,
                                            const float* __restrict__ Wk,
                                            const float* __restrict__ Wv,
                                            const float* __restrict__ Wo,
                                            u16* __restrict__ xb,
                                            u16* __restrict__ fsqb,
                                            u16* __restrict__ posb,
                                            u16* __restrict__ WqT,
                                            u16* __restrict__ WkT,
                                            u16* __restrict__ WvT,
                                            u16* __restrict__ WoT) {
  int bid = blockIdx.x;
  if (bid < 4096) {
    int i = bid * 256 + threadIdx.x;
    const float* src; u16* dst; int off;
    if (i < 524288)      { src = x;   dst = xb;   off = i; }
    else if (i < 786432) { src = fsq; dst = fsqb; off = i - 524288; }
    else                 { src = pos; dst = posb; off = i - 786432; }
    float4 a = ((const float4*)src)[2 * off];
    float4 b = ((const float4*)src)[2 * off + 1];
    ((uint4*)dst)[off] = pack8(a, b);
  } else {
    int id = bid - 4096;
    int z = id >> 8, rest = id & 255;
    int xx = rest & 15, yy = rest >> 4;
    if (z < 3) {
      const float* s = (z == 0) ? Wq : (z == 1) ? Wk : Wv;
      u16* d = (z == 0) ? WqT : (z == 1) ? WkT : WvT;
      size_t off = (size_t)xx * 65536;    // head * 1024 * 64
      transpose_body(s + off, d + off, 1024, 64, yy * 64, 0);
    } else {
      transpose_body(Wo, WoT, 1024, 1024, yy * 64, xx * 64);
    }
  }
}

// ---------------------------------------------------------------------------
// GEMM body: BM = MT*32, BN=128, BK=64, XOR-swizzled LDS, global_load_lds x16.
// LDS chunk (16 B) layout: phys p = r*8 + (c ^ (r & 7)); frag reads cover all
// 8 bank groups over any rows -> conflict-free.  K=N=1024 fixed.
// ---------------------------------------------------------------------------
__device__ __forceinline__ int swz(int R, int c) {   // u16 index of chunk
  return (R * 8 + (c ^ (R & 7))) * 8;
}

template <int MT, bool OUTF32>   // MT = MFMA m-tiles per wave (4 -> BM=128, 2 -> BM=64)
__device__ __forceinline__ void gemm_body(const u16* __restrict__ Ap,
                                          const u16* __restrict__ BT,
                                          const float* __restrict__ bias,
                                          void* Cp, int tile_n) {
  __shared__ u16 As[MT * 32 * 64];
  __shared__ u16 Bs[128 * 64];
  const int t = threadIdx.x, lane = t & 63, wave = t >> 6;
  const int wm = (wave >> 1) * (MT * 16), wn = (wave & 1) * 64;
  const int row16 = lane & 15, quad = lane >> 4;
  const int l8 = lane >> 3;
  const int cswz = (lane & 7) ^ l8;     // source k-chunk for this lane

  f32x4 acc[MT][4] = {};

  for (int k0 = 0; k0 < 1024; k0 += 64) {
    __syncthreads();
#pragma unroll
    for (int j = 0; j < MT; ++j) {
      int r = wave * (MT * 8) + j * 8 + l8;
      gload_lds16(Ap + (size_t)r * 1024 + k0 + cswz * 8,
                  &As[wave * (MT * 512) + j * 512]);
    }
#pragma unroll
    for (int j = 0; j < 4; ++j) {
      int r = wave * 32 + j * 8 + l8;
      gload_lds16(BT + (size_t)(tile_n + r) * 1024 + k0 + cswz * 8,
                  &Bs[wave * 2048 + j * 512]);
    }
    __syncthreads();

#pragma unroll
    for (int kb = 0; kb < 2; ++kb) {
      bf16x8 a_frag[MT], b_frag[4];
#pragma unroll
      for (int i = 0; i < MT; ++i)
        a_frag[i] = *(const bf16x8*)&As[swz(wm + i * 16 + row16, kb * 4 + quad)];
#pragma unroll
      for (int j = 0; j < 4; ++j)
        b_frag[j] = *(const bf16x8*)&Bs[swz(wn + j * 16 + row16, kb * 4 + quad)];
#pragma unroll
      for (int i = 0; i < MT; ++i)
#pragma unroll
        for (int j = 0; j < 4; ++j)
          acc[i][j] = __builtin_amdgcn_mfma_f32_16x16x32_bf16(
              a_frag[i], b_frag[j], acc[i][j], 0, 0, 0);
    }
  }

  // C/D layout: col = lane&15, row = quad*4 + reg
#pragma unroll
  for (int j = 0; j < 4; ++j) {
    int n = tile_n + wn + j * 16 + row16;
    float bb = bias[n];
#pragma unroll
    for (int i = 0; i < MT; ++i) {
      int m0 = wm + i * 16 + quad * 4;
#pragma unroll
      for (int r = 0; r < 4; ++r) {
        float val = acc[i][j][r] + bb;
        if (OUTF32) ((float*)Cp)[(size_t)(m0 + r) * 1024 + n] = val;
        else        ((u16*)Cp)[(size_t)(m0 + r) * 1024 + n] = f2bf(val);
      }
    }
  }
}

// blocks 0..1023 = K/V (A = [xb;fsqb;posb]), 1024..1151 = Q (A = fsqb).
__global__ __launch_bounds__(256) void proj_gemm(const u16* __restrict__ xb,
                                                 const u16* __restrict__ fsqb,
                                                 const u16* __restrict__ posb,
                                                 const u16* __restrict__ WkT,
                                                 const u16* __restrict__ WvT,
                                                 const u16* __restrict__ WqT,
                                                 const float* __restrict__ bk,
                                                 const float* __restrict__ bv,
                                                 const float* __restrict__ bq,
                                                 u16* __restrict__ Kp,
                                                 u16* __restrict__ Vp,
                                                 u16* __restrict__ Qp) {
  int bid = blockIdx.x;
  const u16* Ap; const u16* BT; const float* bias; u16* C; int tile_n;
  if (bid < 1024) {
    int tm = bid >> 4, tn = bid & 15;
    if (tm < 32)      Ap = xb   + (size_t)tm * 128 * 1024;
    else if (tm < 48) Ap = fsqb + (size_t)(tm - 32) * 128 * 1024;
    else              Ap = posb + (size_t)(tm - 48) * 128 * 1024;
    if (tn < 8) { BT = WkT; bias = bk; C = Kp + (size_t)tm * 128 * 1024; tile_n = tn * 128; }
    else        { BT = WvT; bias = bv; C = Vp + (size_t)tm * 128 * 1024; tile_n = (tn - 8) * 128; }
  } else {
    int q = bid - 1024; int tm = q >> 3; tile_n = (q & 7) * 128;
    Ap = fsqb + (size_t)tm * 128 * 1024; BT = WqT; bias = bq;
    C = Qp + (size_t)tm * 128 * 1024;
  }
  gemm_body<4, false>(Ap, BT, bias, C, tile_n);
}

// BM=64 tiles: grid (8, 64) = 512 blocks -> 2+ blocks/CU.
__global__ __launch_bounds__(256) void out_gemm(const u16* __restrict__ Att,
                                                const u16* __restrict__ WoT,
                                                const float* __restrict__ bo,
                                                float* __restrict__ Out) {
  int tile_n = blockIdx.x * 128, tm = blockIdx.y;
  gemm_body<2, true>(Att + (size_t)tm * 64 * 1024, WoT, bo,
                     Out + (size_t)tm * 64 * 1024, tile_n);
}

// ---------------------------------------------------------------------------
// MFMA attention tile: block = (b, h, 32 s-positions).  ~37 KB LDS.
// Tables (u16, row stride 72): Q[32] (reused as P after scores), KW[64],
// VT[64 e][w], KP[32] (pos K), KF[32] (fsq K).
// smP[32][36]: col 0..30 band scores, 31/32 diag scores, 33/34 diag probs.
// Diagonal V rows (pos/fsq) are read from global (L2-hot) in the epilogue.
// ---------------------------------------------------------------------------
#define AST 72
#define QS  0          // 32 rows; becomes P after the softmax barrier
#define KWS 2304       // 64 rows (uses 0..61)
#define VTS 6912       // 64 rows
#define KPS 11520      // 32 rows
#define KFS 13824      // 32 rows
#define SMT 16128

__global__ __launch_bounds__(256) void attn_tile(const u16* __restrict__ Qp,
                                                 const u16* __restrict__ Kp,
                                                 const u16* __restrict__ Vp,
                                                 const float* __restrict__ bk,
                                                 const float* __restrict__ bv,
                                                 u16* __restrict__ Att) {
  __shared__ u16 sm[SMT];
  __shared__ float smP[32 * 36];

  const int t = threadIdx.x;
  const int bid = blockIdx.x;
  const int s0 = (bid & 63) * 32;
  const int h  = (bid >> 6) & 15;
  const int b  = bid >> 10;
  const int lane = t & 63, wave = t >> 6;
  const int row16 = lane & 15, quad = lane >> 4;
  const int hcol = h * 64;

  // ---- staging ----
  { int w = t >> 3, oct = t & 7;                       // Q rows
    *(uint4*)&sm[QS + w * AST + oct * 8] =
        *(const uint4*)(Qp + (size_t)(s0 + w) * 1024 + hcol + oct * 8); }
#pragma unroll
  for (int i = 0; i < 2; ++i) {                        // window K rows
    int task = i * 256 + t; int w = task >> 3, oct = task & 7;
    int g = s0 + w - 15;
    uint4 v;
    if ((unsigned)g < 2048u)
      v = *(const uint4*)(Kp + (size_t)(b * 2048 + g) * 1024 + hcol + oct * 8);
    else
      v = pack8(*(const float4*)(bk + hcol + oct * 8),
                *(const float4*)(bk + hcol + oct * 8 + 4));
    *(uint4*)&sm[KWS + w * AST + oct * 8] = v;
  }
#pragma unroll
  for (int i = 0; i < 2; ++i) {                        // KP (pos) / KF (fsq)
    int task = i * 256 + t;
    int r = (task >> 3) & 31, oct = task & 7;
    size_t grow = (i == 0) ? (size_t)(6144 + s0 + r) : (size_t)(4096 + s0 + r);
    *(uint4*)&sm[(i == 0 ? KPS : KFS) + r * AST + oct * 8] =
        *(const uint4*)(Kp + grow * 1024 + hcol + oct * 8);
  }
#pragma unroll
  for (int i = 0; i < 2; ++i) {                        // window V rows -> VT
    int task = i * 256 + t; int w = task >> 3, oct = task & 7;
    int g = s0 + w - 15;
    union { u16 h8[8]; uint4 q; } u;
    if ((unsigned)g < 2048u)
      u.q = *(const uint4*)(Vp + (size_t)(b * 2048 + g) * 1024 + hcol + oct * 8);
    else
      u.q = pack8(*(const float4*)(bv + hcol + oct * 8),
                  *(const float4*)(bv + hcol + oct * 8 + 4));
#pragma unroll
    for (int j = 0; j < 8; ++j)
      sm[VTS + (oct * 8 + j) * AST + w] = u.h8[j];
  }
  __syncthreads();

  // ---- scores: wave handles key block [wave*16, wave*16+16) ----
  {
    f32x4 accS[2] = {};
#pragma unroll
    for (int kc = 0; kc < 2; ++kc) {
      bf16x8 bf_ = *(const bf16x8*)&sm[KWS + (wave * 16 + row16) * AST + kc * 32 + quad * 8];
#pragma unroll
      for (int mi = 0; mi < 2; ++mi) {
        bf16x8 af = *(const bf16x8*)&sm[QS + (mi * 16 + row16) * AST + kc * 32 + quad * 8];
        accS[mi] = __builtin_amdgcn_mfma_f32_16x16x32_bf16(af, bf_, accS[mi], 0, 0, 0);
      }
    }
#pragma unroll
    for (int mi = 0; mi < 2; ++mi)
#pragma unroll
      for (int r = 0; r < 4; ++r) {
        int s = mi * 16 + quad * 4 + r;
        int w = wave * 16 + row16;
        int d = w - s;
        if (d >= 0 && d <= 30) smP[s * 36 + d] = accS[mi][r] * 0.125f;
      }
  }
  if (t < 64) {                                        // diag scores (pos,fsq)
    int s = t >> 1, which = t & 1;
    int base = (which == 0) ? KPS : KFS;
    float a = 0.f;
#pragma unroll
    for (int c = 0; c < 8; ++c)
      a += dot8(*(const uint4*)&sm[QS + s * AST + c * 8],
                *(const uint4*)&sm[base + s * AST + c * 8]);
    smP[s * 36 + 31 + which] = a * 0.125f;
  }
  __syncthreads();

  // ---- softmax (t<32); P band overwrites Q rows; diag probs stay fp32 ----
  if (t < 32) {
    int s = t;
    float vals[33];
#pragma unroll
    for (int k = 0; k < 33; ++k) vals[k] = smP[s * 36 + k];
    float mx = -1e30f;
#pragma unroll
    for (int k = 0; k < 33; ++k) mx = fmaxf(mx, vals[k]);
    float sum = 0.f;
#pragma unroll
    for (int k = 0; k < 33; ++k) { vals[k] = __expf(vals[k] - mx); sum += vals[k]; }
    float inv = 1.f / sum;
    u32* prow = (u32*)&sm[QS + s * AST];
#pragma unroll
    for (int j = 0; j < 32; ++j) prow[j] = 0;          // zero cols 0..63
#pragma unroll
    for (int k = 0; k < 31; ++k)
      sm[QS + s * AST + s + k] = f2bf(vals[k] * inv);  // band
    smP[s * 36 + 33] = vals[31] * inv;                 // pos
    smP[s * 36 + 34] = vals[32] * inv;                 // fsq
  }
  __syncthreads();

  // ---- PV: wave handles e block [wave*16, wave*16+16) ----
  {
    f32x4 accO[2] = {};
#pragma unroll
    for (int kc = 0; kc < 2; ++kc) {
      bf16x8 bf_ = *(const bf16x8*)&sm[VTS + (wave * 16 + row16) * AST + kc * 32 + quad * 8];
#pragma unroll
      for (int mi = 0; mi < 2; ++mi) {
        bf16x8 af = *(const bf16x8*)&sm[QS + (mi * 16 + row16) * AST + kc * 32 + quad * 8];
        accO[mi] = __builtin_amdgcn_mfma_f32_16x16x32_bf16(af, bf_, accO[mi], 0, 0, 0);
      }
    }
#pragma unroll
    for (int mi = 0; mi < 2; ++mi)
#pragma unroll
      for (int r = 0; r < 4; ++r) {
        int s = mi * 16 + quad * 4 + r;
        int e = wave * 16 + row16;
        float o = accO[mi][r]
                + smP[s * 36 + 33] * bf2f(Vp[(size_t)(6144 + s0 + s) * 1024 + hcol + e])
                + smP[s * 36 + 34] * bf2f(Vp[(size_t)(4096 + s0 + s) * 1024 + hcol + e]);
        Att[(size_t)(b * 2048 + s0 + s) * 1024 + hcol + e] = f2bf(o);
      }
  }
}

// ---------------------------------------------------------------------------
extern "C" void kernel_launch(void* const* d_in, const int* in_sizes, int n_in,
                              void* d_out, int out_size, void* d_ws, size_t ws_size,
                              hipStream_t stream) {
  (void)in_sizes; (void)n_in; (void)out_size; (void)ws_size;

  const float* x   = (const float*)d_in[0];
  const float* fsq = (const float*)d_in[1];
  const float* pos = (const float*)d_in[2];
  const float* Wq  = (const float*)d_in[3];
  const float* bq  = (const float*)d_in[4];
  const float* Wk  = (const float*)d_in[5];
  const float* bk  = (const float*)d_in[6];
  const float* Wv  = (const float*)d_in[7];
  const float* bv  = (const float*)d_in[8];
  const float* Wo  = (const float*)d_in[9];
  const float* bo  = (const float*)d_in[10];

  u16* ws = (u16*)d_ws;
  const size_t M1 = 1024 * 1024;
  u16* WqT  = ws + 0 * M1;   // 1M
  u16* WkT  = ws + 1 * M1;   // 1M
  u16* WvT  = ws + 2 * M1;   // 1M
  u16* WoT  = ws + 3 * M1;   // 1M
  u16* Qp   = ws + 4 * M1;   // 2M : 2048x1024
  u16* Kp   = ws + 6 * M1;   // 8M : 8192x1024
  u16* Vp   = ws + 14 * M1;  // 8M
  u16* fsqb = ws + 22 * M1;  // 2M
  u16* posb = ws + 24 * M1;  // 2M
  u16* xb   = ws + 26 * M1;  // 4M : 4096x1024
  u16* Att  = ws + 22 * M1;  // 4M, aliases fsqb+posb (dead after proj_gemm)
  // peak 30M u16 = 60 MB

  prep<<<5120, 256, 0, stream>>>(x, fsq, pos, Wq, Wk, Wv, Wo,
                                 xb, fsqb, posb, WqT, WkT, WvT, WoT);

  proj_gemm<<<1152, 256, 0, stream>>>(xb, fsqb, posb, WkT, WvT, WqT,
                                      bk, bv, bq, Kp, Vp, Qp);

  attn_tile<<<2048, 256, 0, stream>>>(Qp, Kp, Vp, bk, bv, Att);

  out_gemm<<<dim3(8, 64), 256, 0, stream>>>(Att, WoT, bo, (float*)d_out);
}